// Round 5
// baseline (123.122 us; speedup 1.0000x reference)
//
#include <hip/hip_runtime.h>
#include <cstddef>

#define EPS 1e-5f

constexpr int NG  = 8192;   // genes
constexpr int HID = 32768;  // hidden (= NG*4)
constexpr int NTF = 1024;   // TFs
constexpr int B   = 256;    // batch

typedef __attribute__((address_space(3))) void  lds_void;
typedef __attribute__((address_space(1))) const void g_void;
#define GLDS(gp, lp) __builtin_amdgcn_global_load_lds((g_void*)(gp), (lds_void*)(lp), 4, 0, 0)

// round-to-nearest-even f32 -> bf16 bits (no NaN inputs in this problem)
static __device__ __forceinline__ unsigned short f2bf(float v) {
    union { float f; unsigned u; } a; a.f = v;
    unsigned r = a.u + 0x7fffu + ((a.u >> 16) & 1u);
    return (unsigned short)(r >> 16);
}

// ---------------------------------------------------------------------------
// Kernel 1: fused  sparse-L1 -> relu -> BN1 -> sparse-L2(4x4 blockdiag) -> relu
// Writes relu(h2) TRANSPOSED [HID][B] in bf16, plus per-column invstd2 (BN2
// mean and b3 cancel under BN3's mean subtraction).
// v2: the transposed store is bounced through an LDS tile so each global
// wave-store writes ONE FULL 512-B column (was: 64 scattered 8-B txns/store).
// ---------------------------------------------------------------------------
__global__ __launch_bounds__(256) void fused12(
    const float* __restrict__ x,       // [B][NG]
    const float* __restrict__ w1,      // [HID]
    const float* __restrict__ b1,      // [HID]
    const float* __restrict__ w2,      // [HID*4]
    const float* __restrict__ b2,      // [HID]
    unsigned short* __restrict__ h2rT, // [HID][B] bf16 bits
    float* __restrict__ inv2g)         // [HID]
{
    const int lane  = threadIdx.x & 63;   // column within block tile
    const int slice = threadIdx.x >> 6;   // which 64-row batch slice
    const int c     = (blockIdx.x << 6) + lane;  // global hidden column
    const int g     = c >> 2;             // gene
    const int b0    = slice << 6;

    __shared__ float redA[4][64], redB[4][64];
    __shared__ float m1s[64], inv1s[64];
    __shared__ unsigned short tile[64][260];  // stride 260: 8B-aligned rows,
                                              // 520B = 130 dw, near-conflict-free

    const float w1c = w1[c], b1c = b1[c];
    const float* xp = x + (size_t)b0 * NG + g;

    // ---- phase A: BN1 stats for column c over this thread's 64 rows ----
    float s = 0.f, s2 = 0.f;
    #pragma unroll 8
    for (int i = 0; i < 64; ++i) {
        float h = fmaxf(fmaf(w1c, xp[(size_t)i * NG], b1c), 0.f);
        s += h;
        s2 = fmaf(h, h, s2);
    }
    redA[slice][lane] = s;
    redB[slice][lane] = s2;
    __syncthreads();
    if (slice == 0) {
        float S  = redA[0][lane] + redA[1][lane] + redA[2][lane] + redA[3][lane];
        float S2 = redB[0][lane] + redB[1][lane] + redB[2][lane] + redB[3][lane];
        float m  = S * (1.f / 256.f);
        float v  = fmaf(-m, m, S2 * (1.f / 256.f));
        m1s[lane]   = m;
        inv1s[lane] = rsqrtf(v + EPS);
    }
    __syncthreads();

    // ---- fold BN1 into the 4x4 block weights ----
    const int lbase = lane & ~3;
    const int gbase = g << 2;
    float w1j[4], b1j[4], w2s[4];
    float bconst = b2[c];
    #pragma unroll
    for (int j = 0; j < 4; ++j) {
        w1j[j] = w1[gbase + j];
        b1j[j] = b1[gbase + j];
        float wv = w2[(c << 2) + j] * inv1s[lbase + j];
        w2s[j] = wv;
        bconst = fmaf(-wv, m1s[lbase + j], bconst);
    }

    // ---- phase B: recompute h1, folded L2, relu, BN2 stats, LDS tile ----
    float t2s = 0.f, t2s2 = 0.f;
    for (int i0 = 0; i0 < 64; i0 += 4) {
        ushort4 pk;
        unsigned short* pp = (unsigned short*)&pk;
        #pragma unroll
        for (int u = 0; u < 4; ++u) {
            float v = xp[(size_t)(i0 + u) * NG];
            float acc = bconst;
            #pragma unroll
            for (int j = 0; j < 4; ++j) {
                float r = fmaxf(fmaf(w1j[j], v, b1j[j]), 0.f);
                acc = fmaf(w2s[j], r, acc);
            }
            float r2 = fmaxf(acc, 0.f);
            t2s += r2;
            t2s2 = fmaf(r2, r2, t2s2);
            pp[u] = f2bf(r2);
        }
        *(ushort4*)&tile[lane][b0 + i0] = pk;   // 8 B LDS write
    }

    __syncthreads();                 // tile complete; phase-A redA reads done
    redA[slice][lane] = t2s;
    redB[slice][lane] = t2s2;

    // ---- store phase: wave w writes 16 full columns, 512 B contiguous ----
    {
        const int w = slice;         // wave index
        char* hb = (char*)h2rT;
        #pragma unroll 4
        for (int cc = 0; cc < 16; ++cc) {
            const int cl = (w << 4) + cc;
            ushort4 v = *(const ushort4*)&tile[cl][lane << 2];
            *(ushort4*)(hb + (((size_t)(blockIdx.x << 6) + cl) << 9) + (lane << 3)) = v;
        }
    }

    __syncthreads();
    if (slice == 0) {
        float S  = redA[0][lane] + redA[1][lane] + redA[2][lane] + redA[3][lane];
        float S2 = redB[0][lane] + redB[1][lane] + redB[2][lane] + redB[3][lane];
        float m  = S * (1.f / 256.f);
        float v  = fmaf(-m, m, S2 * (1.f / 256.f));
        inv2g[c] = rsqrtf(v + EPS);
    }
}

// ---------------------------------------------------------------------------
// Prep: fold BN2 invstd into layer-3 weights; precompute column byte offsets.
// ---------------------------------------------------------------------------
__global__ __launch_bounds__(256) void prep3(
    const float* __restrict__ w3,     // [NTF*256]
    const int*   __restrict__ cols3,  // [NTF*256]
    const float* __restrict__ inv2g,  // [HID]
    float* __restrict__ wfold,        // [NTF*256]
    int*   __restrict__ colb)         // [NTF*256] byte offsets
{
    const int i = (blockIdx.x << 8) + threadIdx.x;
    const int col = cols3[i];
    wfold[i] = w3[i] * inv2g[col];
    colb[i]  = col << 9;              // col * B * sizeof(bf16)
}

// ---------------------------------------------------------------------------
// Gather-dot v2: block = (TF t, batch half). The block's 256 columns (256 B
// half-column each) are staged into a 64 KB LDS tile via global_load_lds DMA
// -> data never transits VGPRs, ~63 outstanding loads x 256 B per wave keeps
// the IC pipe full (latency drops out). Then a register dot from LDS.
// ---------------------------------------------------------------------------
__global__ __launch_bounds__(256) void gather3(
    const unsigned short* __restrict__ h2,  // [HID][B] bf16 bits
    const float* __restrict__ wfold,        // [NTF*256]
    const int*   __restrict__ colb,         // [NTF*256] byte offsets
    float* __restrict__ zraw)               // [NTF][B]
{
    const int t    = blockIdx.x >> 1;
    const int half = blockIdx.x & 1;
    const int tid  = threadIdx.x;

    __shared__ unsigned short tile[256][128];  // [e][row] = 64 KB
    __shared__ float wls[256];
    __shared__ float sred[2][128];

    // my edge's column byte-offset (kept in a register for __shfl broadcast)
    const int cb = colb[(t << 8) + tid] + (half << 8);
    wls[tid] = wfold[(t << 8) + tid];

    // ---- stage: wave w DMAs columns e = w*64 .. w*64+63 into LDS ----
    const int w    = tid >> 6;
    const int lane = tid & 63;
    const char* hb = (const char*)h2;
    for (int j = 0; j < 64; ++j) {
        const int e  = (w << 6) + j;
        const int cbe = __shfl(cb, j, 64);        // lanes hold cb[w*64+lane]
        GLDS(hb + cbe + (lane << 2), &tile[e][0]); // 64 lanes x 4 B = 256 B
    }
    __syncthreads();   // drains vmcnt (DMA) before any tile read

    // ---- dot: thread = (e-half, row r); wls/tile reads are broadcasts ----
    const int eh = tid >> 7;
    const int r  = tid & 127;
    float acc = 0.f;
    #pragma unroll 8
    for (int e = 0; e < 128; ++e) {
        const int ee = (eh << 7) + e;
        union { unsigned u; float f; } cv;
        cv.u = (unsigned)tile[ee][r] << 16;
        acc = fmaf(wls[ee], cv.f, acc);
    }
    sred[eh][r] = acc;
    __syncthreads();
    if (tid < 128)
        zraw[(t << 8) + (half << 7) + tid] = sred[0][tid] + sred[1][tid];
}

// ---------------------------------------------------------------------------
// BN3 over the batch for each TF. Per-t constants (b3, BN2-mean correction)
// cancel under the mean subtraction, so zraw needs no bias at all.
// ---------------------------------------------------------------------------
__global__ __launch_bounds__(256) void bn3(
    const float* __restrict__ zraw,   // [NTF][B]
    float* __restrict__ out)          // [B][NTF]
{
    const int t   = blockIdx.x;
    const int tid = threadIdx.x;      // batch row
    __shared__ float rs[4], rs2[4];

    float z = zraw[(t << 8) + tid];
    float s = z, s2 = z * z;
    #pragma unroll
    for (int o = 32; o > 0; o >>= 1) {
        s  += __shfl_xor(s, o);
        s2 += __shfl_xor(s2, o);
    }
    if ((tid & 63) == 0) { rs[tid >> 6] = s; rs2[tid >> 6] = s2; }
    __syncthreads();
    float S  = rs[0] + rs[1] + rs[2] + rs[3];
    float S2 = rs2[0] + rs2[1] + rs2[2] + rs2[3];
    float m  = S * (1.f / 256.f);
    float v  = fmaf(-m, m, S2 * (1.f / 256.f));
    out[(size_t)tid * NTF + t] = (z - m) * rsqrtf(v + EPS);
}

// ---------------------------------------------------------------------------
extern "C" void kernel_launch(void* const* d_in, const int* in_sizes, int n_in,
                              void* d_out, int out_size, void* d_ws, size_t ws_size,
                              hipStream_t stream) {
    const float* x   = (const float*)d_in[0];
    const float* w1  = (const float*)d_in[1];
    const float* b1  = (const float*)d_in[2];
    const float* w2  = (const float*)d_in[3];
    const float* b2  = (const float*)d_in[4];
    const float* w3  = (const float*)d_in[5];
    const float* b3  = (const float*)d_in[6];  (void)b3;  // cancels in BN3
    const int* cols3 = (const int*)d_in[12];
    float* out = (float*)d_out;

    // workspace layout
    unsigned short* h2rT = (unsigned short*)d_ws;                 // 16.8 MB
    float* inv2g = (float*)(h2rT + (size_t)HID * B);              // 128 KB
    float* wfold = inv2g + HID;                                   // 1 MB
    int*   colb  = (int*)(wfold + NTF * 256);                     // 1 MB
    float* zraw  = (float*)(colb + NTF * 256);                    // 1 MB

    fused12<<<HID / 64, 256, 0, stream>>>(x, w1, b1, w2, b2, h2rT, inv2g);
    prep3  <<<NTF,      256, 0, stream>>>(w3, cols3, inv2g, wfold, colb);
    gather3<<<NTF * 2,  256, 0, stream>>>(h2rT, wfold, colb, zraw);
    bn3    <<<NTF,      256, 0, stream>>>(zraw, out);
}